// Round 4
// baseline (558.519 us; speedup 1.0000x reference)
//
#include <hip/hip_runtime.h>
#include <hip/hip_cooperative_groups.h>

namespace cg = cooperative_groups;

#define B_ 16
#define N_ 1024
#define DIN 256
#define K_ 24
#define D_ 128
#define KD_ 3072
#define NSPLIT 16
#define NCHUNK 64
#define EPS_ 1e-7f

// ---- sv phase: t-reduce, s = t@W_k, v = squash(s), w2 = v@W_k^T
// mode 0: first iter (tupart, scale 1/24); 1: mid; 2: last (write out only)
__device__ __forceinline__ void sv_phase(int mode, int beta, int t,
                                         const float* __restrict__ W,
                                         const float* __restrict__ tupart,
                                         const float* __restrict__ tpart,
                                         float* __restrict__ w2,
                                         float* __restrict__ out,
                                         float* Rbuf) {
    float* t_lds = Rbuf;           // 256
    float* v_lds = Rbuf + 256;     // 128 (16B aligned: 256 floats = 1024B)
    float* sred  = Rbuf + 512;     // 512
    float* red2  = Rbuf + 1024;    // 2
    for (int unit = beta; unit < B_ * K_; unit += 256) {
        const int b = unit / K_, k = unit % K_;
        __syncthreads();  // protect Rbuf reuse across loop iterations
        if (t < DIN) {
            float a = 0.f;
            if (mode == 0) {
                #pragma unroll
                for (int s2 = 0; s2 < NSPLIT; ++s2)
                    a += tupart[((size_t)(b * NSPLIT + s2)) * DIN + t];
                a *= (1.0f / 24.0f);
            } else {
                #pragma unroll
                for (int s2 = 0; s2 < NSPLIT; ++s2)
                    a += tpart[((size_t)((b * NSPLIT + s2) * K_ + k)) * DIN + t];
            }
            t_lds[t] = a;
        }
        __syncthreads();
        // s_d = sum_i t[i]*W[i,k*128+d]; 512 thr: d = t&127, i-quarter q = t>>7
        {
            const int d = t & (D_ - 1), q = t >> 7;
            const float* Wp = W + (size_t)(q * 64) * KD_ + (size_t)k * D_ + d;
            const float* tp = t_lds + q * 64;
            float sd = 0.f;
            #pragma unroll 8
            for (int i = 0; i < 64; ++i) sd += tp[i] * Wp[(size_t)i * KD_];
            sred[q * D_ + d] = sd;
        }
        __syncthreads();
        float sd = 0.f;
        if (t < D_) {
            sd = (sred[t] + sred[D_ + t]) + (sred[2 * D_ + t] + sred[3 * D_ + t]);
            float sq = sd * sd;
            #pragma unroll
            for (int m = 1; m < 64; m <<= 1) sq += __shfl_xor(sq, m);
            if ((t & 63) == 0) red2[t >> 6] = sq;
        }
        __syncthreads();
        const float inv = rsqrtf(red2[0] + red2[1] + EPS_);
        if (t < D_) {
            const float vd = sd * inv;
            v_lds[t] = vd;
            if (mode == 2) out[((size_t)(b * K_ + k)) * D_ + t] = vd;
        }
        __syncthreads();
        if (mode != 2 && t < DIN) {
            // w2[i] = sum_d v[d]*W[i,k*128+d], float4 over d
            const float4* Wq = (const float4*)(W + (size_t)t * KD_ + (size_t)k * D_);
            const float4* vq = (const float4*)v_lds;
            float a = 0.f;
            #pragma unroll 8
            for (int q2 = 0; q2 < 32; ++q2) {
                float4 wv = Wq[q2], vv = vq[q2];
                a += wv.x * vv.x + wv.y * vv.y + wv.z * vv.z + wv.w * vv.w;
            }
            w2[((size_t)(b * K_ + k)) * DIN + t] = a;
        }
    }
}

// ---- fused phase: logits + softmax + t-partials for this block's (b,s) chunk
__device__ __forceinline__ void fused_phase(int b, int s, int t,
                                            const float* __restrict__ w2,
                                            float* __restrict__ tpart,
                                            const float* u_lds, float* Rbuf,
                                            float* c_lds) {
    // phase 1: partial logits b[n,k] = sum_i u[n,i]*w2[k,i]
    // acc0/acc1 statically indexed (runtime-indexed reg arrays -> scratch!)
    const float* w2g = w2 + (size_t)b * K_ * DIN;
    {
        const int npair = t & 31, ipart = t >> 5;  // 2 n per thread, 16 i per ipart
        const int n0 = npair * 2, i0 = ipart * 16;
        float acc0[K_], acc1[K_];
        #pragma unroll
        for (int k = 0; k < K_; ++k) { acc0[k] = 0.f; acc1[k] = 0.f; }
        #pragma unroll
        for (int g = 0; g < 4; ++g) {
            float ua0[4], ua1[4];
            #pragma unroll
            for (int m = 0; m < 4; ++m) {
                ua0[m] = u_lds[(n0 + 0) * 257 + i0 + g * 4 + m];
                ua1[m] = u_lds[(n0 + 1) * 257 + i0 + g * 4 + m];
            }
            #pragma unroll
            for (int k = 0; k < K_; ++k) {
                const float4 wq = *(const float4*)(w2g + k * DIN + i0 + g * 4);
                acc0[k] += ua0[0] * wq.x + ua0[1] * wq.y + ua0[2] * wq.z + ua0[3] * wq.w;
                acc1[k] += ua1[0] * wq.x + ua1[1] * wq.y + ua1[2] * wq.z + ua1[3] * wq.w;
            }
        }
        #pragma unroll
        for (int k = 0; k < K_; ++k) {
            acc0[k] += __shfl_xor(acc0[k], 32);
            acc1[k] += __shfl_xor(acc1[k], 32);
        }
        const int w = t >> 6;
        const int hi = (t & 63) >= 32;
        float* sc = Rbuf + (w * NCHUNK + n0 + (hi ? 1 : 0)) * 25;
        #pragma unroll
        for (int k = 0; k < K_; ++k) sc[k] = hi ? acc1[k] : acc0[k];
    }
    __syncthreads();

    // phase 2: reduce 8 wave-partials, softmax over k (8-lane groups, 3 k each)
    {
        const int n = t >> 3, kq = t & 7;
        float lg[3];
        #pragma unroll
        for (int j = 0; j < 3; ++j) {
            float a = 0.f;
            #pragma unroll
            for (int w = 0; w < 8; ++w) a += Rbuf[(w * NCHUNK + n) * 25 + kq * 3 + j];
            lg[j] = a;
        }
        float mx = fmaxf(fmaxf(lg[0], lg[1]), lg[2]);
        #pragma unroll
        for (int m = 1; m < 8; m <<= 1) mx = fmaxf(mx, __shfl_xor(mx, m));
        float e0 = __expf(lg[0] - mx), e1 = __expf(lg[1] - mx), e2 = __expf(lg[2] - mx);
        float sm = e0 + e1 + e2;
        #pragma unroll
        for (int m = 1; m < 8; m <<= 1) sm += __shfl_xor(sm, m);
        const float inv = 1.0f / sm;
        c_lds[n * 32 + kq * 3 + 0] = e0 * inv;
        c_lds[n * 32 + kq * 3 + 1] = e1 * inv;
        c_lds[n * 32 + kq * 3 + 2] = e2 * inv;
    }
    __syncthreads();

    // phase 3: tpart[k][i] = sum_n c[n][k]*u[n][i]
    {
        const int i = t & 255, nh = t >> 8;
        float acc[K_];
        #pragma unroll
        for (int k = 0; k < K_; ++k) acc[k] = 0.f;
        #pragma unroll 4
        for (int n = nh * 32; n < nh * 32 + 32; ++n) {
            const float uv = u_lds[n * 257 + i];
            const float4* cq = (const float4*)(c_lds + n * 32);
            #pragma unroll
            for (int q = 0; q < 6; ++q) {
                float4 cv = cq[q];
                acc[q * 4 + 0] += uv * cv.x;
                acc[q * 4 + 1] += uv * cv.y;
                acc[q * 4 + 2] += uv * cv.z;
                acc[q * 4 + 3] += uv * cv.w;
            }
        }
        __syncthreads();
        if (nh == 1) {
            #pragma unroll
            for (int k = 0; k < K_; ++k) Rbuf[k * 257 + i] = acc[k];
        }
        __syncthreads();
        if (nh == 0) {
            float* tp = tpart + ((size_t)((b * NSPLIT + s) * K_)) * DIN + i;
            #pragma unroll
            for (int k = 0; k < K_; ++k) tp[(size_t)k * DIN] = acc[k] + Rbuf[k * 257 + i];
        }
    }
}

__global__ __launch_bounds__(512, 1) void k_caps(const float* __restrict__ u,
                                                 const float* __restrict__ W,
                                                 float* __restrict__ out,
                                                 float* __restrict__ tupart,
                                                 float* __restrict__ tpart,
                                                 float* __restrict__ w2) {
    cg::grid_group grid = cg::this_grid();
    const int beta = blockIdx.x;
    const int b = beta >> 4, s = beta & 15;
    const int t = threadIdx.x;

    __shared__ float u_lds[NCHUNK * 257];               // 65,792 B (persistent)
    __shared__ __align__(16) float Rbuf[12800];         // 51,200 B (scratch)
    __shared__ __align__(16) float c_lds[NCHUNK * 32];  //  8,192 B

    // ---- P0: stage this block's u chunk into LDS (stays for whole kernel);
    //          colsum -> tupart (iteration-0 t, c uniform)
    {
        const float4* ug = (const float4*)(u + ((size_t)(b * N_ + s * NCHUNK)) * DIN);
        for (int idx = t; idx < NCHUNK * 64; idx += 512) {
            const int n = idx >> 6, q = idx & 63;
            float4 v = ug[(size_t)n * 64 + q];
            float* dst = u_lds + n * 257 + q * 4;
            dst[0] = v.x; dst[1] = v.y; dst[2] = v.z; dst[3] = v.w;
        }
        __syncthreads();
        if (t < DIN) {
            float a = 0.f;
            #pragma unroll
            for (int n = 0; n < NCHUNK; ++n) a += u_lds[n * 257 + t];
            tupart[((size_t)(b * NSPLIT + s)) * DIN + t] = a;
        }
    }
    __threadfence(); grid.sync(); __threadfence();

    // ---- iter 0: s/v/w2
    sv_phase(0, beta, t, W, tupart, tpart, w2, out, Rbuf);
    __threadfence(); grid.sync(); __threadfence();

    // ---- iter 1: logits + softmax + t-partials, then s/v/w2
    fused_phase(b, s, t, w2, tpart, u_lds, Rbuf, c_lds);
    __threadfence(); grid.sync(); __threadfence();
    sv_phase(1, beta, t, W, tupart, tpart, w2, out, Rbuf);
    __threadfence(); grid.sync(); __threadfence();

    // ---- iter 2
    fused_phase(b, s, t, w2, tpart, u_lds, Rbuf, c_lds);
    __threadfence(); grid.sync(); __threadfence();
    sv_phase(2, beta, t, W, tupart, tpart, w2, out, Rbuf);
}

extern "C" void kernel_launch(void* const* d_in, const int* in_sizes, int n_in,
                              void* d_out, int out_size, void* d_ws, size_t ws_size,
                              hipStream_t stream) {
    const float* u = (const float*)d_in[0];   // [16,1024,256]
    const float* W = (const float*)d_in[1];   // [256,3072]
    float* out = (float*)d_out;               // [16,24,128]

    char* ws = (char*)d_ws;
    float* tpart  = (float*)ws;                              // 6,291,456 B
    float* w2     = (float*)(ws + 6291456);                  //   393,216 B
    float* tupart = (float*)(ws + 6291456 + 393216);         //   262,144 B

    void* args[] = {(void*)&u, (void*)&W, (void*)&out,
                    (void*)&tupart, (void*)&tpart, (void*)&w2};
    hipLaunchCooperativeKernel(reinterpret_cast<void*>(k_caps),
                               dim3(256), dim3(512), args, 0, stream);
}

// Round 5
// 186.296 us; speedup vs baseline: 2.9980x; 2.9980x over previous
//
#include <hip/hip_runtime.h>

#define B_ 16
#define N_ 1024
#define DIN 256
#define K_ 24
#define D_ 128
#define KD_ 3072
#define NSPLIT 16
#define NCHUNK 64
#define EPS_ 1e-7f
#define NBLK 256
#define GRPSZ 32
#define NGRP 8

// ---- one-shot hierarchical grid barrier (id = 0..4, each used exactly once)
// layout per id: [g*32] group counters (g=0..7), [256] root. u32 units.
__device__ __forceinline__ void gbar(unsigned* base, int id) {
    __syncthreads();  // drains each wave's stores to L2 (compiler emits vmcnt(0))
    if (threadIdx.x == 0) {
        __threadfence();  // release: push this XCD's dirty L2 to coherence point
        unsigned* grp  = base + id * 512 + (blockIdx.x >> 5) * 32;
        unsigned* root = base + id * 512 + 256;
        unsigned a = __hip_atomic_fetch_add(grp, 1u, __ATOMIC_ACQ_REL,
                                            __HIP_MEMORY_SCOPE_AGENT);
        if (a == GRPSZ - 1)
            __hip_atomic_fetch_add(root, 1u, __ATOMIC_ACQ_REL,
                                   __HIP_MEMORY_SCOPE_AGENT);
        while (__hip_atomic_load(root, __ATOMIC_RELAXED,
                                 __HIP_MEMORY_SCOPE_AGENT) < NGRP)
            __builtin_amdgcn_s_sleep(1);
        __threadfence();  // acquire: invalidate stale cached lines
    }
    __syncthreads();
}

// ---- sv phase: t-reduce, s = t@W_k, v = squash(s), w2 = v@W_k^T
// mode 0: first iter (tupart, scale 1/24); 1: mid; 2: last (write out only)
__device__ __forceinline__ void sv_phase(int mode, int beta, int t,
                                         const float* __restrict__ W,
                                         const float* __restrict__ tupart,
                                         const float* __restrict__ tpart,
                                         float* __restrict__ w2,
                                         float* __restrict__ out,
                                         float* Rbuf) {
    float* t_lds = Rbuf;           // 256
    float* v_lds = Rbuf + 256;     // 128
    float* sred  = Rbuf + 512;     // 512
    float* red2  = Rbuf + 1024;    // 2
    for (int unit = beta; unit < B_ * K_; unit += NBLK) {
        const int b = unit / K_, k = unit % K_;
        __syncthreads();  // protect Rbuf reuse across loop iterations
        if (t < DIN) {
            float a = 0.f;
            if (mode == 0) {
                #pragma unroll
                for (int s2 = 0; s2 < NSPLIT; ++s2)
                    a += tupart[((size_t)(b * NSPLIT + s2)) * DIN + t];
                a *= (1.0f / 24.0f);
            } else {
                #pragma unroll
                for (int s2 = 0; s2 < NSPLIT; ++s2)
                    a += tpart[((size_t)((b * NSPLIT + s2) * K_ + k)) * DIN + t];
            }
            t_lds[t] = a;
        }
        __syncthreads();
        // s_d = sum_i t[i]*W[i,k*128+d]; 512 thr: d = t&127, i-quarter q = t>>7
        {
            const int d = t & (D_ - 1), q = t >> 7;
            const float* Wp = W + (size_t)(q * 64) * KD_ + (size_t)k * D_ + d;
            const float* tp = t_lds + q * 64;
            float sd = 0.f;
            #pragma unroll 8
            for (int i = 0; i < 64; ++i) sd += tp[i] * Wp[(size_t)i * KD_];
            sred[q * D_ + d] = sd;
        }
        __syncthreads();
        float sd = 0.f;
        if (t < D_) {
            sd = (sred[t] + sred[D_ + t]) + (sred[2 * D_ + t] + sred[3 * D_ + t]);
            float sq = sd * sd;
            #pragma unroll
            for (int m = 1; m < 64; m <<= 1) sq += __shfl_xor(sq, m);
            if ((t & 63) == 0) red2[t >> 6] = sq;
        }
        __syncthreads();
        const float inv = rsqrtf(red2[0] + red2[1] + EPS_);
        if (t < D_) {
            const float vd = sd * inv;
            v_lds[t] = vd;
            if (mode == 2) out[((size_t)(b * K_ + k)) * D_ + t] = vd;
        }
        __syncthreads();
        if (mode != 2 && t < DIN) {
            // w2[i] = sum_d v[d]*W[i,k*128+d], float4 over d
            const float4* Wq = (const float4*)(W + (size_t)t * KD_ + (size_t)k * D_);
            const float4* vq = (const float4*)v_lds;
            float a = 0.f;
            #pragma unroll 8
            for (int q2 = 0; q2 < 32; ++q2) {
                float4 wv = Wq[q2], vv = vq[q2];
                a += wv.x * vv.x + wv.y * vv.y + wv.z * vv.z + wv.w * vv.w;
            }
            w2[((size_t)(b * K_ + k)) * DIN + t] = a;
        }
    }
}

// ---- fused phase: logits + softmax + t-partials for this block's (b,s) chunk
__device__ __forceinline__ void fused_phase(int b, int s, int t,
                                            const float* __restrict__ w2,
                                            float* __restrict__ tpart,
                                            const float* u_lds, float* Rbuf,
                                            float* c_lds) {
    // phase 1: partial logits b[n,k] = sum_i u[n,i]*w2[k,i]
    // acc0/acc1 statically indexed (runtime-indexed reg arrays -> scratch!)
    const float* w2g = w2 + (size_t)b * K_ * DIN;
    {
        const int npair = t & 31, ipart = t >> 5;  // 2 n per thread, 16 i per ipart
        const int n0 = npair * 2, i0 = ipart * 16;
        float acc0[K_], acc1[K_];
        #pragma unroll
        for (int k = 0; k < K_; ++k) { acc0[k] = 0.f; acc1[k] = 0.f; }
        #pragma unroll
        for (int g = 0; g < 4; ++g) {
            float ua0[4], ua1[4];
            #pragma unroll
            for (int m = 0; m < 4; ++m) {
                ua0[m] = u_lds[(n0 + 0) * 257 + i0 + g * 4 + m];
                ua1[m] = u_lds[(n0 + 1) * 257 + i0 + g * 4 + m];
            }
            #pragma unroll
            for (int k = 0; k < K_; ++k) {
                const float4 wq = *(const float4*)(w2g + k * DIN + i0 + g * 4);
                acc0[k] += ua0[0] * wq.x + ua0[1] * wq.y + ua0[2] * wq.z + ua0[3] * wq.w;
                acc1[k] += ua1[0] * wq.x + ua1[1] * wq.y + ua1[2] * wq.z + ua1[3] * wq.w;
            }
        }
        #pragma unroll
        for (int k = 0; k < K_; ++k) {
            acc0[k] += __shfl_xor(acc0[k], 32);
            acc1[k] += __shfl_xor(acc1[k], 32);
        }
        const int w = t >> 6;
        const int hi = (t & 63) >= 32;
        float* sc = Rbuf + (w * NCHUNK + n0 + (hi ? 1 : 0)) * 25;
        #pragma unroll
        for (int k = 0; k < K_; ++k) sc[k] = hi ? acc1[k] : acc0[k];
    }
    __syncthreads();

    // phase 2: reduce 8 wave-partials, softmax over k (8-lane groups, 3 k each)
    {
        const int n = t >> 3, kq = t & 7;
        float lg[3];
        #pragma unroll
        for (int j = 0; j < 3; ++j) {
            float a = 0.f;
            #pragma unroll
            for (int w = 0; w < 8; ++w) a += Rbuf[(w * NCHUNK + n) * 25 + kq * 3 + j];
            lg[j] = a;
        }
        float mx = fmaxf(fmaxf(lg[0], lg[1]), lg[2]);
        #pragma unroll
        for (int m = 1; m < 8; m <<= 1) mx = fmaxf(mx, __shfl_xor(mx, m));
        float e0 = __expf(lg[0] - mx), e1 = __expf(lg[1] - mx), e2 = __expf(lg[2] - mx);
        float sm = e0 + e1 + e2;
        #pragma unroll
        for (int m = 1; m < 8; m <<= 1) sm += __shfl_xor(sm, m);
        const float inv = 1.0f / sm;
        c_lds[n * 32 + kq * 3 + 0] = e0 * inv;
        c_lds[n * 32 + kq * 3 + 1] = e1 * inv;
        c_lds[n * 32 + kq * 3 + 2] = e2 * inv;
    }
    __syncthreads();

    // phase 3: tpart[k][i] = sum_n c[n][k]*u[n][i]
    {
        const int i = t & 255, nh = t >> 8;
        float acc[K_];
        #pragma unroll
        for (int k = 0; k < K_; ++k) acc[k] = 0.f;
        #pragma unroll 4
        for (int n = nh * 32; n < nh * 32 + 32; ++n) {
            const float uv = u_lds[n * 257 + i];
            const float4* cq = (const float4*)(c_lds + n * 32);
            #pragma unroll
            for (int q = 0; q < 6; ++q) {
                float4 cv = cq[q];
                acc[q * 4 + 0] += uv * cv.x;
                acc[q * 4 + 1] += uv * cv.y;
                acc[q * 4 + 2] += uv * cv.z;
                acc[q * 4 + 3] += uv * cv.w;
            }
        }
        __syncthreads();
        if (nh == 1) {
            #pragma unroll
            for (int k = 0; k < K_; ++k) Rbuf[k * 257 + i] = acc[k];
        }
        __syncthreads();
        if (nh == 0) {
            float* tp = tpart + ((size_t)((b * NSPLIT + s) * K_)) * DIN + i;
            #pragma unroll
            for (int k = 0; k < K_; ++k) tp[(size_t)k * DIN] = acc[k] + Rbuf[k * 257 + i];
        }
    }
}

__global__ __launch_bounds__(512, 1) void k_caps(const float* __restrict__ u,
                                                 const float* __restrict__ W,
                                                 float* __restrict__ out,
                                                 float* __restrict__ tupart,
                                                 float* __restrict__ tpart,
                                                 float* __restrict__ w2,
                                                 unsigned* __restrict__ bar) {
    const int beta = blockIdx.x;
    const int b = beta >> 4, s = beta & 15;
    const int t = threadIdx.x;

    __shared__ float u_lds[NCHUNK * 257];               // 65,792 B (persistent)
    __shared__ __align__(16) float Rbuf[12800];         // 51,200 B (scratch)
    __shared__ __align__(16) float c_lds[NCHUNK * 32];  //  8,192 B

    // ---- P0: stage this block's u chunk into LDS (stays for whole kernel);
    //          colsum -> tupart (iteration-0 t, c uniform)
    {
        const float4* ug = (const float4*)(u + ((size_t)(b * N_ + s * NCHUNK)) * DIN);
        for (int idx = t; idx < NCHUNK * 64; idx += 512) {
            const int n = idx >> 6, q = idx & 63;
            float4 v = ug[(size_t)n * 64 + q];
            float* dst = u_lds + n * 257 + q * 4;
            dst[0] = v.x; dst[1] = v.y; dst[2] = v.z; dst[3] = v.w;
        }
        __syncthreads();
        if (t < DIN) {
            float a = 0.f;
            #pragma unroll
            for (int n = 0; n < NCHUNK; ++n) a += u_lds[n * 257 + t];
            tupart[((size_t)(b * NSPLIT + s)) * DIN + t] = a;
        }
    }
    gbar(bar, 0);

    // ---- iter 0: s/v/w2
    sv_phase(0, beta, t, W, tupart, tpart, w2, out, Rbuf);
    gbar(bar, 1);

    // ---- iter 1: logits + softmax + t-partials, then s/v/w2
    fused_phase(b, s, t, w2, tpart, u_lds, Rbuf, c_lds);
    gbar(bar, 2);
    sv_phase(1, beta, t, W, tupart, tpart, w2, out, Rbuf);
    gbar(bar, 3);

    // ---- iter 2
    fused_phase(b, s, t, w2, tpart, u_lds, Rbuf, c_lds);
    gbar(bar, 4);
    sv_phase(2, beta, t, W, tupart, tpart, w2, out, Rbuf);
}

extern "C" void kernel_launch(void* const* d_in, const int* in_sizes, int n_in,
                              void* d_out, int out_size, void* d_ws, size_t ws_size,
                              hipStream_t stream) {
    const float* u = (const float*)d_in[0];   // [16,1024,256]
    const float* W = (const float*)d_in[1];   // [256,3072]
    float* out = (float*)d_out;               // [16,24,128]

    char* ws = (char*)d_ws;
    float* tpart    = (float*)ws;                              // 6,291,456 B
    float* w2       = (float*)(ws + 6291456);                  //   393,216 B
    float* tupart   = (float*)(ws + 6291456 + 393216);         //   262,144 B
    unsigned* bar   = (unsigned*)(ws + 6946816);               //    10,240 B

    // zero the barrier counters (captured into the graph, so every replay resets)
    hipMemsetAsync(bar, 0, 5 * 512 * sizeof(unsigned), stream);

    void* args[] = {(void*)&u, (void*)&W, (void*)&out,
                    (void*)&tupart, (void*)&tpart, (void*)&w2, (void*)&bar};
    hipLaunchCooperativeKernel(reinterpret_cast<void*>(k_caps),
                               dim3(NBLK), dim3(512), args, 0, stream);
}

// Round 6
// 104.287 us; speedup vs baseline: 5.3556x; 1.7864x over previous
//
#include <hip/hip_runtime.h>

#define B_ 16
#define N_ 1024
#define DIN 256
#define K_ 24
#define D_ 128
#define KD_ 3072
#define NSPLIT 16
#define NCHUNK 64
#define EPS_ 1e-7f
#define NBLK 256
#define GRPSZ 32
#define NGRP 8

// Coherent (cross-XCD) data accessors: relaxed agent-scope atomics compile to
// single load/store instructions with sc1 (bypass/write-through per-XCD L2).
// No fences needed anywhere -> no buffer_wbl2/buffer_inv storms.
__device__ __forceinline__ float cload(const float* p) {
    return __hip_atomic_load(p, __ATOMIC_RELAXED, __HIP_MEMORY_SCOPE_AGENT);
}
__device__ __forceinline__ void cstore(float* p, float v) {
    __hip_atomic_store(p, v, __ATOMIC_RELAXED, __HIP_MEMORY_SCOPE_AGENT);
}

// ---- one-shot fence-free hierarchical grid barrier (id = 0..4, used once each)
// layout per id: 8 group counters at stride 32, root at [256]. All relaxed.
__device__ __forceinline__ void gbar(unsigned* base, int id) {
    __syncthreads();  // drains this block's (sc1) stores: vmcnt(0) before s_barrier
    if (threadIdx.x == 0) {
        unsigned* grp  = base + id * 512 + (blockIdx.x >> 5) * 32;
        unsigned* root = base + id * 512 + 256;
        asm volatile("" ::: "memory");  // keep data stores before arrival
        unsigned a = __hip_atomic_fetch_add(grp, 1u, __ATOMIC_RELAXED,
                                            __HIP_MEMORY_SCOPE_AGENT);
        if (a == GRPSZ - 1)
            __hip_atomic_fetch_add(root, 1u, __ATOMIC_RELAXED,
                                   __HIP_MEMORY_SCOPE_AGENT);
        while (__hip_atomic_load(root, __ATOMIC_RELAXED,
                                 __HIP_MEMORY_SCOPE_AGENT) < NGRP)
            __builtin_amdgcn_s_sleep(1);
        asm volatile("" ::: "memory");
    }
    __syncthreads();
}

// ---- sv phase: t-reduce, s = t@W_k, v = squash(s), w2 = v@W_k^T
// mode 0: first iter (tupart, scale 1/24); 1: mid; 2: last (write out only)
__device__ __forceinline__ void sv_phase(int mode, int beta, int t,
                                         const float* __restrict__ W,
                                         const float* __restrict__ tupart,
                                         const float* __restrict__ tpart,
                                         float* __restrict__ w2,
                                         float* __restrict__ out,
                                         float* Rbuf) {
    float* t_lds = Rbuf;           // 256
    float* v_lds = Rbuf + 256;     // 128
    float* sred  = Rbuf + 512;     // 512
    float* red2  = Rbuf + 1024;    // 2
    for (int unit = beta; unit < B_ * K_; unit += NBLK) {
        const int b = unit / K_, k = unit % K_;
        __syncthreads();  // protect Rbuf reuse across loop iterations
        if (t < DIN) {
            float a = 0.f;
            if (mode == 0) {
                #pragma unroll
                for (int s2 = 0; s2 < NSPLIT; ++s2)
                    a += cload(tupart + ((size_t)(b * NSPLIT + s2)) * DIN + t);
                a *= (1.0f / 24.0f);
            } else {
                #pragma unroll
                for (int s2 = 0; s2 < NSPLIT; ++s2)
                    a += cload(tpart + ((size_t)((b * NSPLIT + s2) * K_ + k)) * DIN + t);
            }
            t_lds[t] = a;
        }
        __syncthreads();
        // s_d = sum_i t[i]*W[i,k*128+d]; 512 thr: d = t&127, i-quarter q = t>>7
        {
            const int d = t & (D_ - 1), q = t >> 7;
            const float* Wp = W + (size_t)(q * 64) * KD_ + (size_t)k * D_ + d;
            const float* tp = t_lds + q * 64;
            float sd = 0.f;
            #pragma unroll 8
            for (int i = 0; i < 64; ++i) sd += tp[i] * Wp[(size_t)i * KD_];
            sred[q * D_ + d] = sd;
        }
        __syncthreads();
        float sd = 0.f;
        if (t < D_) {
            sd = (sred[t] + sred[D_ + t]) + (sred[2 * D_ + t] + sred[3 * D_ + t]);
            float sq = sd * sd;
            #pragma unroll
            for (int m = 1; m < 64; m <<= 1) sq += __shfl_xor(sq, m);
            if ((t & 63) == 0) red2[t >> 6] = sq;
        }
        __syncthreads();
        const float inv = rsqrtf(red2[0] + red2[1] + EPS_);
        if (t < D_) {
            const float vd = sd * inv;
            v_lds[t] = vd;
            if (mode == 2) out[((size_t)(b * K_ + k)) * D_ + t] = vd;
        }
        __syncthreads();
        if (mode != 2 && t < DIN) {
            // w2[i] = sum_d v[d]*W[i,k*128+d], float4 over d
            const float4* Wq = (const float4*)(W + (size_t)t * KD_ + (size_t)k * D_);
            const float4* vq = (const float4*)v_lds;
            float a = 0.f;
            #pragma unroll 8
            for (int q2 = 0; q2 < 32; ++q2) {
                float4 wv = Wq[q2], vv = vq[q2];
                a += wv.x * vv.x + wv.y * vv.y + wv.z * vv.z + wv.w * vv.w;
            }
            cstore(w2 + ((size_t)(b * K_ + k)) * DIN + t, a);
        }
    }
}

// ---- fused phase: logits + softmax + t-partials for this block's (b,s) chunk
__device__ __forceinline__ void fused_phase(int b, int s, int t,
                                            const float* __restrict__ w2,
                                            float* __restrict__ tpart,
                                            const float* u_lds, float* Rbuf,
                                            float* c_lds, float* w2_lds) {
    // stage w2[b] (24 KB) into LDS once (coherent loads), then read from LDS
    {
        const float* w2g = w2 + (size_t)b * K_ * DIN;
        for (int idx = t; idx < K_ * DIN; idx += 512)
            w2_lds[idx] = cload(w2g + idx);
    }
    __syncthreads();

    // phase 1: partial logits b[n,k] = sum_i u[n,i]*w2[k,i]
    // acc0/acc1 statically indexed (runtime-indexed reg arrays -> scratch!)
    {
        const int npair = t & 31, ipart = t >> 5;  // 2 n per thread, 16 i per ipart
        const int n0 = npair * 2, i0 = ipart * 16;
        float acc0[K_], acc1[K_];
        #pragma unroll
        for (int k = 0; k < K_; ++k) { acc0[k] = 0.f; acc1[k] = 0.f; }
        #pragma unroll
        for (int g = 0; g < 4; ++g) {
            float ua0[4], ua1[4];
            #pragma unroll
            for (int m = 0; m < 4; ++m) {
                ua0[m] = u_lds[(n0 + 0) * 257 + i0 + g * 4 + m];
                ua1[m] = u_lds[(n0 + 1) * 257 + i0 + g * 4 + m];
            }
            #pragma unroll
            for (int k = 0; k < K_; ++k) {
                const float4 wq = *(const float4*)(w2_lds + k * DIN + i0 + g * 4);
                acc0[k] += ua0[0] * wq.x + ua0[1] * wq.y + ua0[2] * wq.z + ua0[3] * wq.w;
                acc1[k] += ua1[0] * wq.x + ua1[1] * wq.y + ua1[2] * wq.z + ua1[3] * wq.w;
            }
        }
        #pragma unroll
        for (int k = 0; k < K_; ++k) {
            acc0[k] += __shfl_xor(acc0[k], 32);
            acc1[k] += __shfl_xor(acc1[k], 32);
        }
        const int w = t >> 6;
        const int hi = (t & 63) >= 32;
        float* sc = Rbuf + (w * NCHUNK + n0 + (hi ? 1 : 0)) * 25;
        #pragma unroll
        for (int k = 0; k < K_; ++k) sc[k] = hi ? acc1[k] : acc0[k];
    }
    __syncthreads();

    // phase 2: reduce 8 wave-partials, softmax over k (8-lane groups, 3 k each)
    {
        const int n = t >> 3, kq = t & 7;
        float lg[3];
        #pragma unroll
        for (int j = 0; j < 3; ++j) {
            float a = 0.f;
            #pragma unroll
            for (int w = 0; w < 8; ++w) a += Rbuf[(w * NCHUNK + n) * 25 + kq * 3 + j];
            lg[j] = a;
        }
        float mx = fmaxf(fmaxf(lg[0], lg[1]), lg[2]);
        #pragma unroll
        for (int m = 1; m < 8; m <<= 1) mx = fmaxf(mx, __shfl_xor(mx, m));
        float e0 = __expf(lg[0] - mx), e1 = __expf(lg[1] - mx), e2 = __expf(lg[2] - mx);
        float sm = e0 + e1 + e2;
        #pragma unroll
        for (int m = 1; m < 8; m <<= 1) sm += __shfl_xor(sm, m);
        const float inv = 1.0f / sm;
        c_lds[n * 32 + kq * 3 + 0] = e0 * inv;
        c_lds[n * 32 + kq * 3 + 1] = e1 * inv;
        c_lds[n * 32 + kq * 3 + 2] = e2 * inv;
    }
    __syncthreads();

    // phase 3: tpart[k][i] = sum_n c[n][k]*u[n][i]
    {
        const int i = t & 255, nh = t >> 8;
        float acc[K_];
        #pragma unroll
        for (int k = 0; k < K_; ++k) acc[k] = 0.f;
        #pragma unroll 4
        for (int n = nh * 32; n < nh * 32 + 32; ++n) {
            const float uv = u_lds[n * 257 + i];
            const float4* cq = (const float4*)(c_lds + n * 32);
            #pragma unroll
            for (int q = 0; q < 6; ++q) {
                float4 cv = cq[q];
                acc[q * 4 + 0] += uv * cv.x;
                acc[q * 4 + 1] += uv * cv.y;
                acc[q * 4 + 2] += uv * cv.z;
                acc[q * 4 + 3] += uv * cv.w;
            }
        }
        __syncthreads();
        if (nh == 1) {
            #pragma unroll
            for (int k = 0; k < K_; ++k) Rbuf[k * 257 + i] = acc[k];
        }
        __syncthreads();
        if (nh == 0) {
            float* tp = tpart + ((size_t)((b * NSPLIT + s) * K_)) * DIN + i;
            #pragma unroll
            for (int k = 0; k < K_; ++k)
                cstore(tp + (size_t)k * DIN, acc[k] + Rbuf[k * 257 + i]);
        }
    }
}

__global__ __launch_bounds__(512, 1) void k_caps(const float* __restrict__ u,
                                                 const float* __restrict__ W,
                                                 float* __restrict__ out,
                                                 float* __restrict__ tupart,
                                                 float* __restrict__ tpart,
                                                 float* __restrict__ w2,
                                                 unsigned* __restrict__ bar) {
    const int beta = blockIdx.x;
    const int b = beta >> 4, s = beta & 15;
    const int t = threadIdx.x;

    __shared__ float u_lds[NCHUNK * 257];               // 65,792 B (persistent)
    __shared__ __align__(16) float Rbuf[12800];         // 51,200 B (scratch)
    __shared__ __align__(16) float c_lds[NCHUNK * 32];  //  8,192 B
    __shared__ __align__(16) float w2_lds[K_ * DIN];    // 24,576 B

    // ---- P0: stage this block's u chunk into LDS (stays for whole kernel);
    //          colsum -> tupart (iteration-0 t, c uniform)
    {
        const float4* ug = (const float4*)(u + ((size_t)(b * N_ + s * NCHUNK)) * DIN);
        for (int idx = t; idx < NCHUNK * 64; idx += 512) {
            const int n = idx >> 6, q = idx & 63;
            float4 v = ug[(size_t)n * 64 + q];
            float* dst = u_lds + n * 257 + q * 4;
            dst[0] = v.x; dst[1] = v.y; dst[2] = v.z; dst[3] = v.w;
        }
        __syncthreads();
        if (t < DIN) {
            float a = 0.f;
            #pragma unroll
            for (int n = 0; n < NCHUNK; ++n) a += u_lds[n * 257 + t];
            cstore(tupart + ((size_t)(b * NSPLIT + s)) * DIN + t, a);
        }
    }
    gbar(bar, 0);

    // ---- iter 0: s/v/w2
    sv_phase(0, beta, t, W, tupart, tpart, w2, out, Rbuf);
    gbar(bar, 1);

    // ---- iter 1: logits + softmax + t-partials, then s/v/w2
    fused_phase(b, s, t, w2, tpart, u_lds, Rbuf, c_lds, w2_lds);
    gbar(bar, 2);
    sv_phase(1, beta, t, W, tupart, tpart, w2, out, Rbuf);
    gbar(bar, 3);

    // ---- iter 2
    fused_phase(b, s, t, w2, tpart, u_lds, Rbuf, c_lds, w2_lds);
    gbar(bar, 4);
    sv_phase(2, beta, t, W, tupart, tpart, w2, out, Rbuf);
}

extern "C" void kernel_launch(void* const* d_in, const int* in_sizes, int n_in,
                              void* d_out, int out_size, void* d_ws, size_t ws_size,
                              hipStream_t stream) {
    const float* u = (const float*)d_in[0];   // [16,1024,256]
    const float* W = (const float*)d_in[1];   // [256,3072]
    float* out = (float*)d_out;               // [16,24,128]

    char* ws = (char*)d_ws;
    float* tpart    = (float*)ws;                              // 6,291,456 B
    float* w2       = (float*)(ws + 6291456);                  //   393,216 B
    float* tupart   = (float*)(ws + 6291456 + 393216);         //   262,144 B
    unsigned* bar   = (unsigned*)(ws + 6946816);               //    10,240 B

    // zero the barrier counters (captured into the graph, so every replay resets)
    hipMemsetAsync(bar, 0, 5 * 512 * sizeof(unsigned), stream);

    void* args[] = {(void*)&u, (void*)&W, (void*)&out,
                    (void*)&tupart, (void*)&tpart, (void*)&w2, (void*)&bar};
    hipLaunchCooperativeKernel(reinterpret_cast<void*>(k_caps),
                               dim3(NBLK), dim3(512), args, 0, stream);
}

// Round 7
// 102.047 us; speedup vs baseline: 5.4732x; 1.0220x over previous
//
#include <hip/hip_runtime.h>

#define B_ 16
#define N_ 1024
#define DIN 256
#define K_ 24
#define D_ 128
#define KD_ 3072
#define NSPLIT 16
#define NCHUNK 64
#define EPS_ 1e-7f
#define NBLK 256
#define NUNIT (B_ * K_)  /* 384 */

// Coherent (cross-XCD) data accessors: relaxed agent-scope atomics -> single
// sc1 load/store instructions (write-through to MALL). No fences anywhere.
__device__ __forceinline__ float cload(const float* p) {
    return __hip_atomic_load(p, __ATOMIC_RELAXED, __HIP_MEMORY_SCOPE_AGENT);
}
__device__ __forceinline__ void cstore(float* p, float v) {
    __hip_atomic_store(p, v, __ATOMIC_RELAXED, __HIP_MEMORY_SCOPE_AGENT);
}

// ---- per-batch producer/consumer flags (one 64B line per flag)
// F1[j][b]: tpart(iter j) ready; target 16 (one per (b,s) producer block)
// F2[j][b]: w2(iter j) ready;   target 24 (one per (b,k) sv unit)
__device__ __forceinline__ unsigned* F1p(unsigned* f, int j, int b) {
    return f + (j * 16 + b) * 16;
}
__device__ __forceinline__ unsigned* F2p(unsigned* f, int j, int b) {
    return f + 768 + (j * 16 + b) * 16;
}
__device__ __forceinline__ void flag_add(unsigned* f) {
    asm volatile("" ::: "memory");
    __hip_atomic_fetch_add(f, 1u, __ATOMIC_RELAXED, __HIP_MEMORY_SCOPE_AGENT);
}
__device__ __forceinline__ void flag_wait(unsigned* f, unsigned target) {
    while (__hip_atomic_load(f, __ATOMIC_RELAXED, __HIP_MEMORY_SCOPE_AGENT) < target)
        __builtin_amdgcn_s_sleep(1);
    asm volatile("" ::: "memory");
}

// ---- sv phase: t-reduce, s = t@W_k, v = squash(s), w2 = v@W_k^T
// iter 0: read tupart (scale 1/24); iter 1: tpart; iter 2: tpart, write out only
__device__ __forceinline__ void sv_phase(int iter, int beta, int t,
                                         const float* __restrict__ W,
                                         const float* __restrict__ tupart,
                                         const float* __restrict__ tpart,
                                         float* __restrict__ w2,
                                         float* __restrict__ out,
                                         float* Rbuf, unsigned* flg) {
    float* t_lds = Rbuf;           // 256
    float* v_lds = Rbuf + 256;     // 128
    float* sred  = Rbuf + 512;     // 512
    float* red2  = Rbuf + 1024;    // 2
    for (int unit = beta; unit < NUNIT; unit += NBLK) {
        const int b = unit / K_, k = unit % K_;
        if (t == 0) flag_wait(F1p(flg, iter, b), 16);
        __syncthreads();  // releases block when t0 sees flag; protects Rbuf reuse
        if (t < DIN) {
            float a = 0.f;
            if (iter == 0) {
                #pragma unroll
                for (int s2 = 0; s2 < NSPLIT; ++s2)
                    a += cload(tupart + ((size_t)(b * NSPLIT + s2)) * DIN + t);
                a *= (1.0f / 24.0f);
            } else {
                #pragma unroll
                for (int s2 = 0; s2 < NSPLIT; ++s2)
                    a += cload(tpart + ((size_t)((b * NSPLIT + s2) * K_ + k)) * DIN + t);
            }
            t_lds[t] = a;
        }
        __syncthreads();
        // s_d = sum_i t[i]*W[i,k*128+d]; 512 thr: d = t&127, i-quarter q = t>>7
        {
            const int d = t & (D_ - 1), q = t >> 7;
            const float* Wp = W + (size_t)(q * 64) * KD_ + (size_t)k * D_ + d;
            const float* tp = t_lds + q * 64;
            float sd = 0.f;
            #pragma unroll 8
            for (int i = 0; i < 64; ++i) sd += tp[i] * Wp[(size_t)i * KD_];
            sred[q * D_ + d] = sd;
        }
        __syncthreads();
        float sd = 0.f;
        if (t < D_) {
            sd = (sred[t] + sred[D_ + t]) + (sred[2 * D_ + t] + sred[3 * D_ + t]);
            float sq = sd * sd;
            #pragma unroll
            for (int m = 1; m < 64; m <<= 1) sq += __shfl_xor(sq, m);
            if ((t & 63) == 0) red2[t >> 6] = sq;
        }
        __syncthreads();
        const float inv = rsqrtf(red2[0] + red2[1] + EPS_);
        if (t < D_) {
            const float vd = sd * inv;
            v_lds[t] = vd;
            if (iter == 2) out[((size_t)(b * K_ + k)) * D_ + t] = vd;
        }
        __syncthreads();
        if (iter != 2) {
            if (t < DIN) {
                // w2[i] = sum_d v[d]*W[i,k*128+d], float4 over d
                const float4* Wq = (const float4*)(W + (size_t)t * KD_ + (size_t)k * D_);
                const float4* vq = (const float4*)v_lds;
                float a = 0.f;
                #pragma unroll 8
                for (int q2 = 0; q2 < 32; ++q2) {
                    float4 wv = Wq[q2], vv = vq[q2];
                    a += wv.x * vv.x + wv.y * vv.y + wv.z * vv.z + wv.w * vv.w;
                }
                cstore(w2 + ((size_t)(b * K_ + k)) * DIN + t, a);
            }
            __syncthreads();  // drain w2 stores (vmcnt 0 per wave) before flagging
            if (t == 0) flag_add(F2p(flg, iter, b));
        }
    }
}

// ---- fused phase: logits + softmax + t-partials for this block's (b,s) chunk
__device__ __forceinline__ void fused_phase(int iter, int b, int s, int t,
                                            const float* __restrict__ w2,
                                            float* __restrict__ tpart,
                                            const float* u_lds, float* Rbuf,
                                            float* c_lds, float* w2_lds,
                                            unsigned* flg) {
    if (t == 0) flag_wait(F2p(flg, iter - 1, b), 24);
    __syncthreads();
    // stage w2[b] (24 KB) into LDS once (coherent loads)
    {
        const float* w2g = w2 + (size_t)b * K_ * DIN;
        for (int idx = t; idx < K_ * DIN; idx += 512)
            w2_lds[idx] = cload(w2g + idx);
    }
    __syncthreads();

    // phase 1: partial logits b[n,k] = sum_i u[n,i]*w2[k,i]
    // acc0/acc1 statically indexed (runtime-indexed reg arrays -> scratch!)
    {
        const int npair = t & 31, ipart = t >> 5;  // 2 n per thread, 16 i per ipart
        const int n0 = npair * 2, i0 = ipart * 16;
        float acc0[K_], acc1[K_];
        #pragma unroll
        for (int k = 0; k < K_; ++k) { acc0[k] = 0.f; acc1[k] = 0.f; }
        #pragma unroll
        for (int g = 0; g < 4; ++g) {
            float ua0[4], ua1[4];
            #pragma unroll
            for (int m = 0; m < 4; ++m) {
                ua0[m] = u_lds[(n0 + 0) * 257 + i0 + g * 4 + m];
                ua1[m] = u_lds[(n0 + 1) * 257 + i0 + g * 4 + m];
            }
            #pragma unroll
            for (int k = 0; k < K_; ++k) {
                const float4 wq = *(const float4*)(w2_lds + k * DIN + i0 + g * 4);
                acc0[k] += ua0[0] * wq.x + ua0[1] * wq.y + ua0[2] * wq.z + ua0[3] * wq.w;
                acc1[k] += ua1[0] * wq.x + ua1[1] * wq.y + ua1[2] * wq.z + ua1[3] * wq.w;
            }
        }
        #pragma unroll
        for (int k = 0; k < K_; ++k) {
            acc0[k] += __shfl_xor(acc0[k], 32);
            acc1[k] += __shfl_xor(acc1[k], 32);
        }
        const int w = t >> 6;
        const int hi = (t & 63) >= 32;
        float* sc = Rbuf + (w * NCHUNK + n0 + (hi ? 1 : 0)) * 25;
        #pragma unroll
        for (int k = 0; k < K_; ++k) sc[k] = hi ? acc1[k] : acc0[k];
    }
    __syncthreads();

    // phase 2: reduce 8 wave-partials, softmax over k (8-lane groups, 3 k each)
    {
        const int n = t >> 3, kq = t & 7;
        float lg[3];
        #pragma unroll
        for (int j = 0; j < 3; ++j) {
            float a = 0.f;
            #pragma unroll
            for (int w = 0; w < 8; ++w) a += Rbuf[(w * NCHUNK + n) * 25 + kq * 3 + j];
            lg[j] = a;
        }
        float mx = fmaxf(fmaxf(lg[0], lg[1]), lg[2]);
        #pragma unroll
        for (int m = 1; m < 8; m <<= 1) mx = fmaxf(mx, __shfl_xor(mx, m));
        float e0 = __expf(lg[0] - mx), e1 = __expf(lg[1] - mx), e2 = __expf(lg[2] - mx);
        float sm = e0 + e1 + e2;
        #pragma unroll
        for (int m = 1; m < 8; m <<= 1) sm += __shfl_xor(sm, m);
        const float inv = 1.0f / sm;
        c_lds[n * 32 + kq * 3 + 0] = e0 * inv;
        c_lds[n * 32 + kq * 3 + 1] = e1 * inv;
        c_lds[n * 32 + kq * 3 + 2] = e2 * inv;
    }
    __syncthreads();

    // phase 3: tpart[k][i] = sum_n c[n][k]*u[n][i]
    {
        const int i = t & 255, nh = t >> 8;
        float acc[K_];
        #pragma unroll
        for (int k = 0; k < K_; ++k) acc[k] = 0.f;
        #pragma unroll 4
        for (int n = nh * 32; n < nh * 32 + 32; ++n) {
            const float uv = u_lds[n * 257 + i];
            const float4* cq = (const float4*)(c_lds + n * 32);
            #pragma unroll
            for (int q = 0; q < 6; ++q) {
                float4 cv = cq[q];
                acc[q * 4 + 0] += uv * cv.x;
                acc[q * 4 + 1] += uv * cv.y;
                acc[q * 4 + 2] += uv * cv.z;
                acc[q * 4 + 3] += uv * cv.w;
            }
        }
        __syncthreads();
        if (nh == 1) {
            #pragma unroll
            for (int k = 0; k < K_; ++k) Rbuf[k * 257 + i] = acc[k];
        }
        __syncthreads();
        if (nh == 0) {
            float* tp = tpart + ((size_t)((b * NSPLIT + s) * K_)) * DIN + i;
            #pragma unroll
            for (int k = 0; k < K_; ++k)
                cstore(tp + (size_t)k * DIN, acc[k] + Rbuf[k * 257 + i]);
        }
    }
    __syncthreads();  // drain tpart stores before flagging
    if (t == 0) flag_add(F1p(flg, iter, b));
}

__global__ __launch_bounds__(512, 1) void k_caps(const float* __restrict__ u,
                                                 const float* __restrict__ W,
                                                 float* __restrict__ out,
                                                 float* __restrict__ tupart,
                                                 float* __restrict__ tpart,
                                                 float* __restrict__ w2,
                                                 unsigned* __restrict__ flg) {
    const int beta = blockIdx.x;
    const int b = beta >> 4, s = beta & 15;
    const int t = threadIdx.x;

    __shared__ float u_lds[NCHUNK * 257];               // 65,792 B (persistent)
    __shared__ __align__(16) float Rbuf[12800];         // 51,200 B (scratch)
    __shared__ __align__(16) float c_lds[NCHUNK * 32];  //  8,192 B
    __shared__ __align__(16) float w2_lds[K_ * DIN];    // 24,576 B

    // ---- P0: stage this block's u chunk into LDS (persistent); colsum -> tupart
    {
        const float4* ug = (const float4*)(u + ((size_t)(b * N_ + s * NCHUNK)) * DIN);
        for (int idx = t; idx < NCHUNK * 64; idx += 512) {
            const int n = idx >> 6, q = idx & 63;
            float4 v = ug[(size_t)n * 64 + q];
            float* dst = u_lds + n * 257 + q * 4;
            dst[0] = v.x; dst[1] = v.y; dst[2] = v.z; dst[3] = v.w;
        }
        __syncthreads();
        if (t < DIN) {
            float a = 0.f;
            #pragma unroll
            for (int n = 0; n < NCHUNK; ++n) a += u_lds[n * 257 + t];
            cstore(tupart + ((size_t)(b * NSPLIT + s)) * DIN + t, a);
        }
        __syncthreads();  // drain tupart stores
        if (t == 0) flag_add(F1p(flg, 0, b));
    }

    // ---- iter 0
    sv_phase(0, beta, t, W, tupart, tpart, w2, out, Rbuf, flg);
    // ---- iter 1
    fused_phase(1, b, s, t, w2, tpart, u_lds, Rbuf, c_lds, w2_lds, flg);
    sv_phase(1, beta, t, W, tupart, tpart, w2, out, Rbuf, flg);
    // ---- iter 2
    fused_phase(2, b, s, t, w2, tpart, u_lds, Rbuf, c_lds, w2_lds, flg);
    sv_phase(2, beta, t, W, tupart, tpart, w2, out, Rbuf, flg);
}

extern "C" void kernel_launch(void* const* d_in, const int* in_sizes, int n_in,
                              void* d_out, int out_size, void* d_ws, size_t ws_size,
                              hipStream_t stream) {
    const float* u = (const float*)d_in[0];   // [16,1024,256]
    const float* W = (const float*)d_in[1];   // [256,3072]
    float* out = (float*)d_out;               // [16,24,128]

    char* ws = (char*)d_ws;
    float* tpart    = (float*)ws;                              // 6,291,456 B
    float* w2       = (float*)(ws + 6291456);                  //   393,216 B
    float* tupart   = (float*)(ws + 6291456 + 393216);         //   262,144 B
    unsigned* flg   = (unsigned*)(ws + 6946816);               //     6,144 B

    // zero the flags (captured into the graph, so every replay resets them)
    hipMemsetAsync(flg, 0, 6144, stream);

    void* args[] = {(void*)&u, (void*)&W, (void*)&out,
                    (void*)&tupart, (void*)&tpart, (void*)&w2, (void*)&flg};
    hipLaunchCooperativeKernel(reinterpret_cast<void*>(k_caps),
                               dim3(NBLK), dim3(512), args, 0, stream);
}